// Round 1
// baseline (8371.802 us; speedup 1.0000x reference)
//
#include <hip/hip_runtime.h>
#include <cstdint>
#include <cstddef>

typedef _Float16 f16;
typedef _Float16 f16x4 __attribute__((ext_vector_type(4)));
typedef float f32x4 __attribute__((ext_vector_type(4)));

#define MFMA16(a, b, c) __builtin_amdgcn_mfma_f32_16x16x16f16((a), (b), (c), 0, 0, 0)

constexpr int TT = 1024, DIN = 128, DH = 512, DOUT = 128;
constexpr size_t O_ELEMS = (size_t)64 * 1024 * 128;

__device__ __forceinline__ uint32_t swz(uint32_t row, uint32_t byteoff) {
    // XOR-swizzle within a 1024B row: spreads 16 rows over all 32 banks (<=2-way)
    return byteoff ^ ((row & 7u) << 4) ^ ((row & 8u) << 2);
}

// ---------------- Pass 1: xI = X(65536x128) @ wI(128x512) -> H region (fp32) ----------------
__global__ __launch_bounds__(256, 1) void k_xI(const float* __restrict__ X,
                                               const float* __restrict__ wI,
                                               float* __restrict__ xI) {
    __shared__ __align__(16) f16 Bt[DH][136];  // wI^T [n][k], padded stride
    __shared__ __align__(16) f16 At[64][136];  // X tile [m][k], padded stride
    const int tid = threadIdx.x;
    const int wv = tid >> 6, ln = tid & 63, l15 = ln & 15, g = ln >> 4;
    const int m0 = (int)blockIdx.x * 64;

    // stage B (transpose to [n][k]): 128x512 fp32 -> f16
    for (int u = 0; u < 64; ++u) {
        int flat = u * 256 + tid;       // 0..16383
        int r = flat >> 7;              // k row 0..127
        int c4 = (flat & 127) << 2;     // n col 0..508
        const float4 w4 = *(const float4*)(wI + (size_t)r * DH + c4);
        Bt[c4 + 0][r] = (f16)w4.x;
        Bt[c4 + 1][r] = (f16)w4.y;
        Bt[c4 + 2][r] = (f16)w4.z;
        Bt[c4 + 3][r] = (f16)w4.w;
    }
    // stage A: 64x128 fp32 -> f16
    {
        int r = tid >> 2;
        int cb = (tid & 3) << 5;
        #pragma unroll
        for (int u = 0; u < 8; ++u) {
            int c = cb + u * 4;
            const float4 x4 = *(const float4*)(X + (size_t)(m0 + r) * DIN + c);
            f16x4 h4;
            h4[0] = (f16)x4.x; h4[1] = (f16)x4.y; h4[2] = (f16)x4.z; h4[3] = (f16)x4.w;
            *(f16x4*)((char*)&At[r][0] + c * 2) = h4;
        }
    }
    __syncthreads();

    f32x4 acc[4][8];
    #pragma unroll
    for (int mt = 0; mt < 4; ++mt)
        #pragma unroll
        for (int nt = 0; nt < 8; ++nt) acc[mt][nt] = (f32x4){0.f, 0.f, 0.f, 0.f};

    #pragma unroll
    for (int c = 0; c < 8; ++c) {
        const int k0 = c * 16 + g * 4;
        f16x4 a[4];
        #pragma unroll
        for (int mt = 0; mt < 4; ++mt)
            a[mt] = *(const f16x4*)((const char*)&At[mt * 16 + l15][0] + k0 * 2);
        #pragma unroll
        for (int nt = 0; nt < 8; ++nt) {
            const int n = wv * 128 + nt * 16 + l15;
            const f16x4 b = *(const f16x4*)((const char*)&Bt[n][0] + k0 * 2);
            #pragma unroll
            for (int mt = 0; mt < 4; ++mt) acc[mt][nt] = MFMA16(a[mt], b, acc[mt][nt]);
        }
    }
    #pragma unroll
    for (int mt = 0; mt < 4; ++mt) {
        #pragma unroll
        for (int i = 0; i < 4; ++i) {
            const int m = m0 + mt * 16 + g * 4 + i;
            float* orow = xI + (size_t)m * DH + wv * 128 + l15;
            #pragma unroll
            for (int nt = 0; nt < 8; ++nt) orow[nt * 16] = acc[mt][nt][i];
        }
    }
}

// ---------------- Pass 2: the recurrent scan (4 blocks, 16 batches each) ----------------
// In place on the H region: reads xI[b,t,:], writes H[b,t,:] into the same slots.
__global__ __launch_bounds__(256, 1) void k_scan(const float* __restrict__ wR,
                                                 const float* __restrict__ h0,
                                                 float* __restrict__ Hb) {
    __shared__ __align__(16) f16 Bl[8][16][512];  // 128 KiB: [tile][j-in-tile][k] swizzled
    __shared__ __align__(16) f16 hb[16][512];     // 16 KiB:  [batch][k] swizzled

    const int tid = threadIdx.x;
    const int wv = tid >> 6, ln = tid & 63, l15 = ln & 15, g = ln >> 4;
    const int bb = (int)blockIdx.x * 16;

    // ---- stage wR: 6 register j-tiles per wave (384 VGPR), 2 LDS j-tiles per wave ----
    f16x4 Brf[6][32];
    #pragma unroll
    for (int q = 0; q < 6; ++q) {
        const int j = wv * 128 + q * 16 + l15;
        #pragma unroll
        for (int c = 0; c < 32; ++c) {
            const int k = c * 16 + g * 4;
            const float* p = wR + (size_t)k * DH + j;
            f16x4 v;
            v[0] = (f16)p[0];
            v[1] = (f16)p[DH];
            v[2] = (f16)p[2 * DH];
            v[3] = (f16)p[3 * DH];
            Brf[q][c] = v;
        }
    }
    {
        char* base = (char*)Bl + (size_t)(wv * 2) * 16384;
        for (int idx = ln; idx < 32 * 512; idx += 64) {
            const int jj = idx & 31;
            const int k = idx >> 5;
            const float v = wR[(size_t)k * DH + wv * 128 + 96 + jj];
            const int row = jj & 15;
            const int tile = jj >> 4;
            *(f16*)(base + tile * 16384 + row * 1024 + swz(row, (uint32_t)(k * 2))) = (f16)v;
        }
    }
    // ---- h0 broadcast to all 16 batch rows ----
    for (int j = tid; j < DH; j += 256) {
        const f16 v = (f16)h0[j];
        #pragma unroll
        for (int r = 0; r < 16; ++r)
            *(f16*)((char*)hb + r * 1024 + swz((uint32_t)r, (uint32_t)(j * 2))) = v;
    }
    __syncthreads();

    float* Hrow[4];
    #pragma unroll
    for (int i = 0; i < 4; ++i) Hrow[i] = Hb + (size_t)(bb + g * 4 + i) * TT * DH;

    const int jbase = wv * 128 + l15;
    const uint32_t swA = ((uint32_t)(l15 & 7) << 4) ^ ((uint32_t)(l15 & 8) << 2);
    const char* hbp = (const char*)hb + l15 * 1024;
    const char* b6p = (const char*)Bl + (size_t)(wv * 2) * 16384 + l15 * 1024;
    const char* b7p = b6p + 16384;

    f32x4 acc[8];
    #pragma unroll
    for (int q = 0; q < 8; ++q) acc[q] = (f32x4){0.f, 0.f, 0.f, 0.f};

    #pragma unroll 1
    for (int t = 0; t < TT; ++t) {
        // deferred H stores of step t-1 (overlap with this step's MFMA phase)
        if (t > 0) {
            #pragma unroll
            for (int q = 0; q < 8; ++q)
                #pragma unroll
                for (int i = 0; i < 4; ++i)
                    Hrow[i][(size_t)(t - 1) * DH + jbase + q * 16] = acc[q][i];
        }
        // prefetch xI for this step (consumed after barrier 1)
        float xv[8][4];
        #pragma unroll
        for (int q = 0; q < 8; ++q)
            #pragma unroll
            for (int i = 0; i < 4; ++i)
                xv[q][i] = Hrow[i][(size_t)t * DH + jbase + q * 16];

        #pragma unroll
        for (int q = 0; q < 8; ++q) acc[q] = (f32x4){0.f, 0.f, 0.f, 0.f};

        // h @ wR : 32 k-chunks x 8 j-tiles
        #pragma unroll
        for (int c = 0; c < 32; ++c) {
            const uint32_t kb = (uint32_t)(c * 32 + g * 8);  // disjoint bits: c*32 | g*8
            const f16x4 a = *(const f16x4*)(hbp + (kb ^ swA));
            #pragma unroll
            for (int q = 0; q < 6; ++q) acc[q] = MFMA16(a, Brf[q][c], acc[q]);
            const f16x4 b6 = *(const f16x4*)(b6p + (kb ^ swA));
            acc[6] = MFMA16(a, b6, acc[6]);
            const f16x4 b7 = *(const f16x4*)(b7p + (kb ^ swA));
            acc[7] = MFMA16(a, b7, acc[7]);
        }
        __syncthreads();  // all hb reads done

        // epilogue: tanh(acc + xI); keep fp32 in acc for deferred store; fp16 into hb
        #pragma unroll
        for (int q = 0; q < 8; ++q) {
            const int j = jbase + q * 16;
            #pragma unroll
            for (int i = 0; i < 4; ++i) {
                const int r = g * 4 + i;
                const float x = acc[q][i] + xv[q][i];
                const float e = exp2f(x * 2.8853900817779268f);  // e^(2x)
                const float th = 1.0f - 2.0f / (e + 1.0f);
                acc[q][i] = th;
                *(f16*)((char*)hb + r * 1024 + swz((uint32_t)r, (uint32_t)(j * 2))) = (f16)th;
            }
        }
        __syncthreads();  // hb writes visible before next step's reads
    }
    // final stores (t = TT-1)
    #pragma unroll
    for (int q = 0; q < 8; ++q)
        #pragma unroll
        for (int i = 0; i < 4; ++i)
            Hrow[i][(size_t)(TT - 1) * DH + jbase + q * 16] = acc[q][i];
}

// ---------------- Pass 3: O = H(65536x512) @ wO(512x128) ----------------
__global__ __launch_bounds__(256, 1) void k_O(const float* __restrict__ H,
                                              const float* __restrict__ wO,
                                              float* __restrict__ O) {
    __shared__ __align__(16) f16 Bt[DOUT][520];  // wO^T [n][k]
    __shared__ __align__(16) f16 At[64][136];    // H tile [m][k-chunk]
    const int tid = threadIdx.x;
    const int wv = tid >> 6, ln = tid & 63, l15 = ln & 15, g = ln >> 4;
    const int m0 = (int)blockIdx.x * 64;

    // stage B (transpose): 512x128 fp32 -> f16 [n][k]
    for (int u = 0; u < 64; ++u) {
        int flat = u * 256 + tid;    // 0..16383
        int r = flat >> 5;           // k 0..511
        int c4 = (flat & 31) << 2;   // n 0..124
        const float4 w4 = *(const float4*)(wO + (size_t)r * DOUT + c4);
        Bt[c4 + 0][r] = (f16)w4.x;
        Bt[c4 + 1][r] = (f16)w4.y;
        Bt[c4 + 2][r] = (f16)w4.z;
        Bt[c4 + 3][r] = (f16)w4.w;
    }

    f32x4 acc[8];
    #pragma unroll
    for (int nt = 0; nt < 8; ++nt) acc[nt] = (f32x4){0.f, 0.f, 0.f, 0.f};

    for (int kc = 0; kc < 4; ++kc) {
        __syncthreads();  // prev chunk's reads done (covers B staging for kc=0)
        {
            int r = tid >> 2;
            int cb = (tid & 3) << 5;
            #pragma unroll
            for (int u = 0; u < 8; ++u) {
                int c = cb + u * 4;
                const float4 x4 = *(const float4*)(H + (size_t)(m0 + r) * DH + kc * 128 + c);
                f16x4 h4;
                h4[0] = (f16)x4.x; h4[1] = (f16)x4.y; h4[2] = (f16)x4.z; h4[3] = (f16)x4.w;
                *(f16x4*)((char*)&At[r][0] + c * 2) = h4;
            }
        }
        __syncthreads();
        #pragma unroll
        for (int c = 0; c < 8; ++c) {
            const int k0 = c * 16 + g * 4;
            const f16x4 a = *(const f16x4*)((const char*)&At[wv * 16 + l15][0] + k0 * 2);
            #pragma unroll
            for (int nt = 0; nt < 8; ++nt) {
                const f16x4 b =
                    *(const f16x4*)((const char*)&Bt[nt * 16 + l15][0] + (kc * 128 + k0) * 2);
                acc[nt] = MFMA16(a, b, acc[nt]);
            }
        }
    }
    #pragma unroll
    for (int i = 0; i < 4; ++i) {
        const int m = m0 + wv * 16 + g * 4 + i;
        #pragma unroll
        for (int nt = 0; nt < 8; ++nt) O[(size_t)m * DOUT + nt * 16 + l15] = acc[nt][i];
    }
}

extern "C" void kernel_launch(void* const* d_in, const int* in_sizes, int n_in,
                              void* d_out, int out_size, void* d_ws, size_t ws_size,
                              hipStream_t stream) {
    const float* X  = (const float*)d_in[0];
    const float* h0 = (const float*)d_in[1];
    const float* wI = (const float*)d_in[2];
    const float* wR = (const float*)d_in[3];
    const float* wO = (const float*)d_in[4];
    float* O = (float*)d_out;
    float* H = O + O_ELEMS;  // H region of d_out; also holds xI before in-place scan

    k_xI<<<1024, 256, 0, stream>>>(X, wI, H);   // xI -> H region
    k_scan<<<4, 256, 0, stream>>>(wR, h0, H);   // in-place: xI -> H
    k_O<<<1024, 256, 0, stream>>>(H, wO, O);    // O = H @ wO
}